// Round 4
// baseline (316.064 us; speedup 1.0000x reference)
//
#include <hip/hip_runtime.h>
#include <math.h>

#define B_ 64
#define S_ 256
#define V_ 2048
#define NS 12
#define ZOFF 0.001f
#define EPSF 1e-8f
#define EPS2 1e-16f
#define NCH 32   // v-chunks in latch phase (64 elems each)

// ws layout (float offsets, 16-aligned)
#define WS_NSP2 0
#define WS_D0   64                     // [B]
#define WS_N0   (WS_D0 + B_)           // [B]
#define WS_E    256                    // [B*S]
#define WS_R    (WS_E + B_*S_)         // [B*S]
#define WS_NX2  (WS_R + B_*S_)         // [B*S]
#define WS_H    (WS_NX2 + B_*S_)       // [B][NCH][S][2]
#define WS_COEF (WS_H + B_*NCH*S_*2)   // [B][S][13][4]
// coef layout per (b,t): n<12: (A,B,C,P), n==12: (pop,0,0,0)

// sum across a DPP row of 16 lanes via rotate-adds (VALU-speed, no DS ops)
__device__ __forceinline__ float row16_sum(float x) {
    int t;
    t = __builtin_amdgcn_update_dpp(0, __float_as_int(x), 0x121, 0xf, 0xf, true);
    x += __int_as_float(t);  // ror:1
    t = __builtin_amdgcn_update_dpp(0, __float_as_int(x), 0x122, 0xf, 0xf, true);
    x += __int_as_float(t);  // ror:2
    t = __builtin_amdgcn_update_dpp(0, __float_as_int(x), 0x124, 0xf, 0xf, true);
    x += __int_as_float(t);  // ror:4
    t = __builtin_amdgcn_update_dpp(0, __float_as_int(x), 0x128, 0xf, 0xf, true);
    x += __int_as_float(t);  // ror:8
    return x;
}

// full 64-lane sum: 4 DPP + 2 ds shuffles (vs 6 ds for shfl_xor ladder)
__device__ __forceinline__ float wave_sum64_fast(float x) {
    x = row16_sum(x);
    x += __shfl_xor(x, 16);
    x += __shfl_xor(x, 32);
    return x;
}

// ---------- Phase A0: ||sp||^2 (blk 0) + per-batch d0/n0 (blks 1..64) ----------
__global__ void __launch_bounds__(256) k_norms(const float* __restrict__ sp,
                        const float* __restrict__ l0,
                        float* __restrict__ ws) {
    __shared__ float red[4][2];
    int tid = threadIdx.x;
    int blk = blockIdx.x;
    float a = 0.f, b = 0.f;
    if (blk == 0) {
        for (int i = tid; i < V_; i += 256) { float y = sp[i]; a += y * y; }
    } else {
        const float* lr = l0 + (size_t)(blk - 1) * V_;
        for (int i = tid; i < V_; i += 256) {
            float l = lr[i], s = sp[i];
            a += s * l; b += l * l;
        }
    }
    a = wave_sum64_fast(a); b = wave_sum64_fast(b);
    int wave = tid >> 6, lane = tid & 63;
    if (lane == 0) { red[wave][0] = a; red[wave][1] = b; }
    __syncthreads();
    if (tid == 0) {
        float s0 = red[0][0] + red[1][0] + red[2][0] + red[3][0];
        float s1 = red[0][1] + red[1][1] + red[2][1] + red[3][1];
        if (blk == 0) ws[WS_NSP2] = s0;
        else { ws[WS_D0 + blk - 1] = s0; ws[WS_N0 + blk - 1] = s1; }
    }
}

// ---------- Phase A: per (b,t): e_t, r_t = sp.x_t, nx2_t = ||x_t||^2 ----------
__global__ void __launch_bounds__(256) k_e(const float* __restrict__ x,
                                           const float* __restrict__ le,
                                           const float* __restrict__ sp,
                                           float* __restrict__ ws) {
    int bt = blockIdx.x;  // b*S + t
    const float4* xb = (const float4*)(x + (size_t)bt * V_);
    const float4* le4 = (const float4*)le;
    const float4* sp4 = (const float4*)sp;
    int tid = threadIdx.x;
    float dot = 0.f, nx = 0.f, rr = 0.f, nle = 0.f;
#pragma unroll
    for (int k = 0; k < 2; k++) {
        int i = tid + k * 256;
        float4 xv = xb[i], lv = le4[i], sv = sp4[i];
        dot += xv.x * lv.x + xv.y * lv.y + xv.z * lv.z + xv.w * lv.w;
        nx  += xv.x * xv.x + xv.y * xv.y + xv.z * xv.z + xv.w * xv.w;
        rr  += xv.x * sv.x + xv.y * sv.y + xv.z * sv.z + xv.w * sv.w;
        nle += lv.x * lv.x + lv.y * lv.y + lv.z * lv.z + lv.w * lv.w;
    }
    dot = wave_sum64_fast(dot); nx = wave_sum64_fast(nx);
    rr = wave_sum64_fast(rr);   nle = wave_sum64_fast(nle);
    __shared__ float red[4][4];
    int wave = tid >> 6, lane = tid & 63;
    if (lane == 0) {
        red[wave][0] = dot; red[wave][1] = nx;
        red[wave][2] = rr;  red[wave][3] = nle;
    }
    __syncthreads();
    if (tid == 0) {
        float d  = red[0][0] + red[1][0] + red[2][0] + red[3][0];
        float n  = red[0][1] + red[1][1] + red[2][1] + red[3][1];
        float r  = red[0][2] + red[1][2] + red[2][2] + red[3][2];
        float nl = red[0][3] + red[1][3] + red[2][3] + red[3][3];
        ws[WS_E + bt]   = d * __frsqrt_rn(fmaxf(nl, EPS2)) * __frsqrt_rn(fmaxf(n, EPS2));
        ws[WS_R + bt]   = r;
        ws[WS_NX2 + bt] = n;
    }
}

// ---------- Phase B: latch scan; h-reduction via DPP + 1 ds fold ----------
__global__ void __launch_bounds__(64) k_latch(const float* __restrict__ x,
                        const float* __restrict__ latch_init,
                        float* __restrict__ latch_out,
                        float* __restrict__ ws) {
    int c = blockIdx.x, b = blockIdx.y;
    int lane = threadIdx.x;
    int v = c * 64 + lane;

    __shared__ float se[S_];
    for (int t = lane; t < S_; t += 64) se[t] = ws[WS_E + b * S_ + t];
    __syncthreads();

    float latch = latch_init[b * V_ + v];
    const float* xb = x + (size_t)b * S_ * V_ + v;
    float* lo = latch_out + (size_t)b * S_ * V_ + v;
    float* hpp = ws + WS_H + (size_t)(b * NCH + c) * S_ * 2;
    int hrow = lane >> 5;            // 0 or 1 (which 32-lane half)
    bool hwr = (lane & 31) == 0;     // lanes 0 and 32 store

    auto step = [&](int t, float xv, float e) {
        // h_t partial: dot over this wave's 64 v's, folded to 2 half-sums
        float rs = row16_sum(latch * xv);
        rs += __shfl_xor(rs, 16);
        if (hwr) hpp[t * 2 + hrow] = rs;
        latch = fmaf(e, xv - latch, latch);   // (1-e)*latch + e*x
        __builtin_nontemporal_store(latch, lo + (size_t)t * V_);
    };

    float xc[8], ec[8];
#pragma unroll
    for (int k = 0; k < 8; k++) { xc[k] = xb[(size_t)k * V_]; ec[k] = se[k]; }
    for (int t = 0; t < S_; t += 8) {
        float y[8], f[8];
        if (t + 8 < S_) {
#pragma unroll
            for (int k = 0; k < 8; k++) {
                y[k] = xb[(size_t)(t + 8 + k) * V_];
                f[k] = se[t + 8 + k];
            }
        } else {
#pragma unroll
            for (int k = 0; k < 8; k++) { y[k] = 0.f; f[k] = 0.f; }
        }
#pragma unroll
        for (int k = 0; k < 8; k++) step(t + k, xc[k], ec[k]);
#pragma unroll
        for (int k = 0; k < 8; k++) { xc[k] = y[k]; ec[k] = f[k]; }
    }
}

// ---------- Phase C: scalar d/n recurrences + pointer softmax -> coefs ----------
__global__ void __launch_bounds__(64) k_pointer(const float* __restrict__ sharpen_ptr,
                          float* __restrict__ ws,
                          float* __restrict__ pops_out) {
    int b = blockIdx.x, lane = threadIdx.x;
    __shared__ float sh[S_], se_[S_], sr_[S_], snx_[S_];
    const float2* hp2 = (const float2*)(ws + WS_H) + (size_t)b * NCH * S_;
    for (int t = lane; t < S_; t += 64) {
        float h = 0.f;
#pragma unroll
        for (int c = 0; c < NCH; c++) { float2 vv = hp2[(size_t)c * S_ + t]; h += vv.x + vv.y; }
        sh[t] = h;
        se_[t]  = ws[WS_E + b * S_ + t];
        sr_[t]  = ws[WS_R + b * S_ + t];
        snx_[t] = ws[WS_NX2 + b * S_ + t];
    }
    __syncthreads();

    float sharpen = sharpen_ptr[0];
    float inv_nsp = 1.f / fmaxf(sqrtf(ws[WS_NSP2]), EPSF);
    float d = ws[WS_D0 + b];
    float n = ws[WS_N0 + b];
    float p = (lane == 0) ? 1.f : 0.f;
    float* coef = ws + WS_COEF + (size_t)b * S_ * 13 * 4;

    int nm1 = (lane == 0) ? 11 : lane - 1;    // (n-1) mod 12
    int np1 = (lane == 11) ? 0 : lane + 1;    // (n+1) mod 12

    for (int t = 0; t < S_; t++) {
        // pop from cossim(sp, latch state entering step t)
        float cs = d * inv_nsp * __frsqrt_rn(fmaxf(n, EPS2));
        float pop = cs > 0.f ? cs : __expf(cs) - 1.f;
        float push = 1.f - pop;
        // softmax over 12 lanes of the 16-lane row (DPP rotate-add sum)
        float ez = (lane < NS) ? __expf(p * sharpen) : 0.f;
        float s = row16_sum(ez);
        float psh = ez * __frcp_rn(s);
        float push_p = __shfl(psh, nm1);
        float pop_p  = __shfl(psh, np1);
        float bb = push * push_p;
        float cc = pop * psh;
        float a  = 1.f - bb - cc;
        float pnew = fmaf(pop, pop_p, bb);
        if (lane < NS) {
            float4* dst = (float4*)(coef + (size_t)(t * 13 + lane) * 4);
            *dst = make_float4(a, bb, cc * ZOFF, pnew);
        } else if (lane == NS) {
            float4* dst = (float4*)(coef + (size_t)(t * 13 + 12) * 4);
            *dst = make_float4(pop, 0.f, 0.f, 0.f);
        }
        if (lane == 0) pops_out[b * S_ + t] = pop;
        p = pnew;
        // advance d/n to state entering step t+1
        float e = se_[t], om = 1.f - e;
        d = fmaf(om, d, e * sr_[t]);
        n = om * om * n + 2.f * e * om * sh[t] + e * e * snx_[t];
    }
}

// ---------- Phase D: stack scan; coefs via uniform global loads, ping-pong regs ----------
#define LOADC(CB, T) do { \
    const float4* p4_ = (const float4*)(cbg + (size_t)(T) * 52); \
    _Pragma("unroll") \
    for (int j_ = 0; j_ < 13; j_++) CB[j_] = p4_[j_]; \
} while (0)

#define DSTEP(CB, T, XV) do { \
    float top_ = 0.f; \
    _Pragma("unroll") \
    for (int n_ = 0; n_ < NS; n_++) { \
        float4 c4_ = CB[n_]; \
        st[n_] = fmaf(c4_.x, st[n_], fmaf(c4_.y, (XV), c4_.z)); \
        top_ = fmaf(c4_.w, st[n_], top_); \
    } \
    float pop_ = CB[12].x; \
    __builtin_nontemporal_store(top_, tp + (size_t)(T) * V_); \
    __builtin_nontemporal_store(pop_ * top_, op + (size_t)(T) * V_); \
} while (0)

__global__ void __launch_bounds__(256) k_stack(const float* __restrict__ x,
                                               const float* __restrict__ ws,
                                               float* __restrict__ outputs,
                                               float* __restrict__ tops) {
    int b = blockIdx.y, ch = blockIdx.x;
    int tid = threadIdx.x;
    const float* cbg = ws + WS_COEF + (size_t)b * S_ * 52;  // wave-uniform

    int v = ch * 256 + tid;
    const float* xp = x + (size_t)b * S_ * V_ + v;
    float* op = outputs + (size_t)b * S_ * V_ + v;
    float* tp = tops + (size_t)b * S_ * V_ + v;

    float st[NS];
#pragma unroll
    for (int n = 0; n < NS; n++) st[n] = ZOFF;

    float4 A[13], Bb[13];
    LOADC(A, 0);
    float xr0 = __builtin_nontemporal_load(xp);
    float xr1 = __builtin_nontemporal_load(xp + (size_t)V_);
    float xr2 = __builtin_nontemporal_load(xp + 2 * (size_t)V_);
    float xr3 = __builtin_nontemporal_load(xp + 3 * (size_t)V_);
    for (int t = 0; t < S_; t += 2) {
        LOADC(Bb, t + 1);
        float y0 = 0.f, y1 = 0.f;
        if (t + 4 < S_) {
            y0 = __builtin_nontemporal_load(xp + (size_t)(t + 4) * V_);
            y1 = __builtin_nontemporal_load(xp + (size_t)(t + 5) * V_);
        }
        DSTEP(A, t, xr0);
        if (t + 2 < S_) LOADC(A, t + 2);
        DSTEP(Bb, t + 1, xr1);
        xr0 = xr2; xr1 = xr3; xr2 = y0; xr3 = y1;
    }
}

extern "C" void kernel_launch(void* const* d_in, const int* in_sizes, int n_in,
                              void* d_out, int out_size, void* d_ws, size_t ws_size,
                              hipStream_t stream) {
    const float* x           = (const float*)d_in[0];
    const float* latch_init  = (const float*)d_in[1];
    const float* should_pop  = (const float*)d_in[2];
    const float* sharpen_ptr = (const float*)d_in[3];
    const float* latch_en    = (const float*)d_in[4];

    float* out = (float*)d_out;
    const size_t BSV = (size_t)B_ * S_ * V_;
    float* outputs      = out;
    float* latch_states = out + BSV;
    float* pops         = out + 2 * BSV;
    float* tops         = out + 2 * BSV + (size_t)B_ * S_;
    float* ws = (float*)d_ws;

    k_norms<<<B_ + 1, 256, 0, stream>>>(should_pop, latch_init, ws);
    k_e<<<B_ * S_, 256, 0, stream>>>(x, latch_en, should_pop, ws);
    k_latch<<<dim3(NCH, B_), 64, 0, stream>>>(x, latch_init, latch_states, ws);
    k_pointer<<<B_, 64, 0, stream>>>(sharpen_ptr, ws, pops);
    k_stack<<<dim3(8, B_), 256, 0, stream>>>(x, ws, outputs, tops);
}

// Round 5
// 217.788 us; speedup vs baseline: 1.4512x; 1.4512x over previous
//
#include <hip/hip_runtime.h>
#include <math.h>

#define B_ 64
#define S_ 256
#define V_ 2048
#define NS 12
#define ZOFF 0.001f
#define EPSF 1e-8f
#define EPS2 1e-16f
#define NCH 32   // v-chunks in latch phase (64 elems each)

// ws layout (float offsets, 16-aligned)
#define WS_NSP2 0
#define WS_D0   64                     // [B]
#define WS_N0   (WS_D0 + B_)           // [B]
#define WS_E    256                    // [B*S]
#define WS_R    (WS_E + B_*S_)         // [B*S]
#define WS_NX2  (WS_R + B_*S_)         // [B*S]
#define WS_H    (WS_NX2 + B_*S_)       // [B][NCH][S][2]
#define WS_COEF (WS_H + B_*NCH*S_*2)   // [B][S][13][4]
// coef layout per (b,t): n<12: (A,B,C,P), n==12: (pop,0,0,0)

// sum across a DPP row of 16 lanes via rotate-adds (VALU-speed, no DS ops)
__device__ __forceinline__ float row16_sum(float x) {
    int t;
    t = __builtin_amdgcn_update_dpp(0, __float_as_int(x), 0x121, 0xf, 0xf, true);
    x += __int_as_float(t);  // ror:1
    t = __builtin_amdgcn_update_dpp(0, __float_as_int(x), 0x122, 0xf, 0xf, true);
    x += __int_as_float(t);  // ror:2
    t = __builtin_amdgcn_update_dpp(0, __float_as_int(x), 0x124, 0xf, 0xf, true);
    x += __int_as_float(t);  // ror:4
    t = __builtin_amdgcn_update_dpp(0, __float_as_int(x), 0x128, 0xf, 0xf, true);
    x += __int_as_float(t);  // ror:8
    return x;
}

// full 64-lane sum: 4 DPP + 2 ds shuffles (vs 6 ds for shfl_xor ladder)
__device__ __forceinline__ float wave_sum64_fast(float x) {
    x = row16_sum(x);
    x += __shfl_xor(x, 16);
    x += __shfl_xor(x, 32);
    return x;
}

__device__ __forceinline__ float2 ntload2(const float2* p) {
    double d = __builtin_nontemporal_load((const double*)p);
    return __builtin_bit_cast(float2, d);
}
__device__ __forceinline__ void ntstore2(float2* p, float a, float b) {
    float2 v = make_float2(a, b);
    __builtin_nontemporal_store(__builtin_bit_cast(double, v), (double*)p);
}

// ---------- Phase A (merged): e/r/nx2 per (b,t) + sp/batch norms ----------
// blocks [0, B*S): e-path. block B*S: ||sp||^2. blocks B*S+1 .. B*S+B: d0/n0.
__global__ void __launch_bounds__(256) k_e(const float* __restrict__ x,
                                           const float* __restrict__ le,
                                           const float* __restrict__ sp,
                                           const float* __restrict__ l0,
                                           float* __restrict__ ws) {
    int blk = blockIdx.x;
    int tid = threadIdx.x;
    int wave = tid >> 6, lane = tid & 63;
    if (blk >= B_ * S_) {
        // norms path
        __shared__ float red[4][2];
        int nb = blk - B_ * S_;
        float a = 0.f, b = 0.f;
        if (nb == 0) {
            for (int i = tid; i < V_; i += 256) { float y = sp[i]; a += y * y; }
        } else {
            const float* lr = l0 + (size_t)(nb - 1) * V_;
            for (int i = tid; i < V_; i += 256) {
                float l = lr[i], s = sp[i];
                a += s * l; b += l * l;
            }
        }
        a = wave_sum64_fast(a); b = wave_sum64_fast(b);
        if (lane == 0) { red[wave][0] = a; red[wave][1] = b; }
        __syncthreads();
        if (tid == 0) {
            float s0 = red[0][0] + red[1][0] + red[2][0] + red[3][0];
            float s1 = red[0][1] + red[1][1] + red[2][1] + red[3][1];
            if (nb == 0) ws[WS_NSP2] = s0;
            else { ws[WS_D0 + nb - 1] = s0; ws[WS_N0 + nb - 1] = s1; }
        }
        return;
    }
    int bt = blk;  // b*S + t
    const float4* xb = (const float4*)(x + (size_t)bt * V_);
    const float4* le4 = (const float4*)le;
    const float4* sp4 = (const float4*)sp;
    float dot = 0.f, nx = 0.f, rr = 0.f, nle = 0.f;
#pragma unroll
    for (int k = 0; k < 2; k++) {
        int i = tid + k * 256;
        float4 xv = xb[i], lv = le4[i], sv = sp4[i];
        dot += xv.x * lv.x + xv.y * lv.y + xv.z * lv.z + xv.w * lv.w;
        nx  += xv.x * xv.x + xv.y * xv.y + xv.z * xv.z + xv.w * xv.w;
        rr  += xv.x * sv.x + xv.y * sv.y + xv.z * sv.z + xv.w * sv.w;
        nle += lv.x * lv.x + lv.y * lv.y + lv.z * lv.z + lv.w * lv.w;
    }
    dot = wave_sum64_fast(dot); nx = wave_sum64_fast(nx);
    rr = wave_sum64_fast(rr);   nle = wave_sum64_fast(nle);
    __shared__ float red4[4][4];
    if (lane == 0) {
        red4[wave][0] = dot; red4[wave][1] = nx;
        red4[wave][2] = rr;  red4[wave][3] = nle;
    }
    __syncthreads();
    if (tid == 0) {
        float d  = red4[0][0] + red4[1][0] + red4[2][0] + red4[3][0];
        float n  = red4[0][1] + red4[1][1] + red4[2][1] + red4[3][1];
        float r  = red4[0][2] + red4[1][2] + red4[2][2] + red4[3][2];
        float nl = red4[0][3] + red4[1][3] + red4[2][3] + red4[3][3];
        ws[WS_E + bt]   = d * __frsqrt_rn(fmaxf(nl, EPS2)) * __frsqrt_rn(fmaxf(n, EPS2));
        ws[WS_R + bt]   = r;
        ws[WS_NX2 + bt] = n;
    }
}

// ---------- Phase B: latch scan; h-reduction via DPP + 1 ds fold ----------
__global__ void __launch_bounds__(64) k_latch(const float* __restrict__ x,
                        const float* __restrict__ latch_init,
                        float* __restrict__ latch_out,
                        float* __restrict__ ws) {
    int c = blockIdx.x, b = blockIdx.y;
    int lane = threadIdx.x;
    int v = c * 64 + lane;

    __shared__ float se[S_];
    for (int t = lane; t < S_; t += 64) se[t] = ws[WS_E + b * S_ + t];
    __syncthreads();

    float latch = latch_init[b * V_ + v];
    const float* xb = x + (size_t)b * S_ * V_ + v;
    float* lo = latch_out + (size_t)b * S_ * V_ + v;
    float* hpp = ws + WS_H + (size_t)(b * NCH + c) * S_ * 2;
    int hrow = lane >> 5;            // 0 or 1 (which 32-lane half)
    bool hwr = (lane & 31) == 0;     // lanes 0 and 32 store

    auto step = [&](int t, float xv, float e) {
        // h_t partial: dot over this wave's 64 v's, folded to 2 half-sums
        float rs = row16_sum(latch * xv);
        rs += __shfl_xor(rs, 16);
        if (hwr) hpp[t * 2 + hrow] = rs;
        latch = fmaf(e, xv - latch, latch);   // (1-e)*latch + e*x
        __builtin_nontemporal_store(latch, lo + (size_t)t * V_);
    };

    float xc[8], ec[8];
#pragma unroll
    for (int k = 0; k < 8; k++) { xc[k] = xb[(size_t)k * V_]; ec[k] = se[k]; }
    for (int t = 0; t < S_; t += 8) {
        float y[8], f[8];
        if (t + 8 < S_) {
#pragma unroll
            for (int k = 0; k < 8; k++) {
                y[k] = xb[(size_t)(t + 8 + k) * V_];
                f[k] = se[t + 8 + k];
            }
        } else {
#pragma unroll
            for (int k = 0; k < 8; k++) { y[k] = 0.f; f[k] = 0.f; }
        }
#pragma unroll
        for (int k = 0; k < 8; k++) step(t + k, xc[k], ec[k]);
#pragma unroll
        for (int k = 0; k < 8; k++) { xc[k] = y[k]; ec[k] = f[k]; }
    }
}

// ---------- Phase C: scalar d/n recurrences + pointer softmax -> coefs ----------
__global__ void __launch_bounds__(64) k_pointer(const float* __restrict__ sharpen_ptr,
                          float* __restrict__ ws,
                          float* __restrict__ pops_out) {
    int b = blockIdx.x, lane = threadIdx.x;
    __shared__ float sh[S_], se_[S_], sr_[S_], snx_[S_];
    const float2* hp2 = (const float2*)(ws + WS_H) + (size_t)b * NCH * S_;
    for (int t = lane; t < S_; t += 64) {
        float h = 0.f;
#pragma unroll
        for (int c = 0; c < NCH; c++) { float2 vv = hp2[(size_t)c * S_ + t]; h += vv.x + vv.y; }
        sh[t] = h;
        se_[t]  = ws[WS_E + b * S_ + t];
        sr_[t]  = ws[WS_R + b * S_ + t];
        snx_[t] = ws[WS_NX2 + b * S_ + t];
    }
    __syncthreads();

    float sharpen = sharpen_ptr[0];
    float inv_nsp = 1.f / fmaxf(sqrtf(ws[WS_NSP2]), EPSF);
    float d = ws[WS_D0 + b];
    float n = ws[WS_N0 + b];
    float p = (lane == 0) ? 1.f : 0.f;
    float* coef = ws + WS_COEF + (size_t)b * S_ * 13 * 4;

    int nm1 = (lane == 0) ? 11 : lane - 1;    // (n-1) mod 12
    int np1 = (lane == 11) ? 0 : lane + 1;    // (n+1) mod 12

    for (int t = 0; t < S_; t++) {
        // pop from cossim(sp, latch state entering step t)
        float cs = d * inv_nsp * __frsqrt_rn(fmaxf(n, EPS2));
        float pop = cs > 0.f ? cs : __expf(cs) - 1.f;
        float push = 1.f - pop;
        // softmax over 12 lanes of the 16-lane row (DPP rotate-add sum)
        float ez = (lane < NS) ? __expf(p * sharpen) : 0.f;
        float s = row16_sum(ez);
        float psh = ez * __frcp_rn(s);
        float push_p = __shfl(psh, nm1);
        float pop_p  = __shfl(psh, np1);
        float bb = push * push_p;
        float cc = pop * psh;
        float a  = 1.f - bb - cc;
        float pnew = fmaf(pop, pop_p, bb);
        if (lane < NS) {
            float4* dst = (float4*)(coef + (size_t)(t * 13 + lane) * 4);
            *dst = make_float4(a, bb, cc * ZOFF, pnew);
        } else if (lane == NS) {
            float4* dst = (float4*)(coef + (size_t)(t * 13 + 12) * 4);
            *dst = make_float4(pop, 0.f, 0.f, 0.f);
        }
        if (lane == 0) pops_out[b * S_ + t] = pop;
        p = pnew;
        // advance d/n to state entering step t+1
        float e = se_[t], om = 1.f - e;
        d = fmaf(om, d, e * sr_[t]);
        n = om * om * n + 2.f * e * om * sh[t] + e * e * snx_[t];
    }
}

// ---------- Phase D: stack scan; LDS coefs, 2 v-elems/thread ----------
__global__ void __launch_bounds__(256) k_stack(const float* __restrict__ x,
                                               const float* __restrict__ ws,
                                               float* __restrict__ outputs,
                                               float* __restrict__ tops) {
    int b = blockIdx.y, ch = blockIdx.x;   // ch in [0,4)
    int tid = threadIdx.x;
    __shared__ float sc[S_ * 52];
    const float4* cb4 = (const float4*)(ws + WS_COEF + (size_t)b * S_ * 52);
    float4* sc4 = (float4*)sc;
#pragma unroll
    for (int i = 0; i < 13; i++) sc4[tid + 256 * i] = cb4[tid + 256 * i];
    __syncthreads();

    int v = ch * 512 + tid * 2;
    const float2* xp = (const float2*)(x + (size_t)b * S_ * V_ + v);
    float2* op = (float2*)(outputs + (size_t)b * S_ * V_ + v);
    float2* tp = (float2*)(tops + (size_t)b * S_ * V_ + v);
    const int VS = V_ / 2;   // float2 stride per t

    float st0[NS], st1[NS];
#pragma unroll
    for (int n = 0; n < NS; n++) { st0[n] = ZOFF; st1[n] = ZOFF; }

    auto dstep = [&](int t, float2 xv) {
        const float* cf = &sc[t * 52];
        float top0 = 0.f, top1 = 0.f;
#pragma unroll
        for (int n = 0; n < NS; n++) {
            float4 c4 = *(const float4*)(cf + n * 4);
            float bx0 = fmaf(c4.y, xv.x, c4.z);
            float bx1 = fmaf(c4.y, xv.y, c4.z);
            st0[n] = fmaf(c4.x, st0[n], bx0);
            st1[n] = fmaf(c4.x, st1[n], bx1);
            top0 = fmaf(c4.w, st0[n], top0);
            top1 = fmaf(c4.w, st1[n], top1);
        }
        float pop = cf[48];
        ntstore2(tp + (size_t)t * VS, top0, top1);
        ntstore2(op + (size_t)t * VS, pop * top0, pop * top1);
    };

    float2 xr0 = ntload2(xp);
    float2 xr1 = ntload2(xp + VS);
    float2 xr2 = ntload2(xp + 2 * VS);
    float2 xr3 = ntload2(xp + 3 * VS);
    for (int t = 0; t < S_; t += 4) {
        float2 y0 = make_float2(0.f, 0.f), y1 = y0, y2 = y0, y3 = y0;
        if (t + 4 < S_) {
            y0 = ntload2(xp + (size_t)(t + 4) * VS);
            y1 = ntload2(xp + (size_t)(t + 5) * VS);
            y2 = ntload2(xp + (size_t)(t + 6) * VS);
            y3 = ntload2(xp + (size_t)(t + 7) * VS);
        }
        dstep(t + 0, xr0); dstep(t + 1, xr1);
        dstep(t + 2, xr2); dstep(t + 3, xr3);
        xr0 = y0; xr1 = y1; xr2 = y2; xr3 = y3;
    }
}

extern "C" void kernel_launch(void* const* d_in, const int* in_sizes, int n_in,
                              void* d_out, int out_size, void* d_ws, size_t ws_size,
                              hipStream_t stream) {
    const float* x           = (const float*)d_in[0];
    const float* latch_init  = (const float*)d_in[1];
    const float* should_pop  = (const float*)d_in[2];
    const float* sharpen_ptr = (const float*)d_in[3];
    const float* latch_en    = (const float*)d_in[4];

    float* out = (float*)d_out;
    const size_t BSV = (size_t)B_ * S_ * V_;
    float* outputs      = out;
    float* latch_states = out + BSV;
    float* pops         = out + 2 * BSV;
    float* tops         = out + 2 * BSV + (size_t)B_ * S_;
    float* ws = (float*)d_ws;

    k_e<<<B_ * S_ + 1 + B_, 256, 0, stream>>>(x, latch_en, should_pop, latch_init, ws);
    k_latch<<<dim3(NCH, B_), 64, 0, stream>>>(x, latch_init, latch_states, ws);
    k_pointer<<<B_, 64, 0, stream>>>(sharpen_ptr, ws, pops);
    k_stack<<<dim3(4, B_), 256, 0, stream>>>(x, ws, outputs, tops);
}